// Round 9
// baseline (6101.299 us; speedup 1.0000x reference)
//
#include <hip/hip_runtime.h>
#include <hip/hip_fp16.h>
#include <stdint.h>

// Problem: x[16,2048,512] f32, embed[4096,512] f32.
// encode: idx[n] = argmax_k (x.e_k - 0.5||e_k||^2); decode: embed[idx].
// d_out (float): [0,32768) = idx, [32768,+32768*512) = quantize.
//
// Stage 1 (vq_main): hi-f16 MFMA GEMM, A-tile LDS-RESIDENT (staged once: 32 MB
// total HBM), B streamed from L2 in dbuf [256][32] tiles with counted vmcnt.
// 512 thr / 8 waves (2/SIMD), 64x64 wave tiles (8 ds_read per 16 MFMA).
// Per-row top-3 tracked; cross-wave merge via LDS scratch.
// esq loads are NORMAL loads (compiler-tracked). NOTE: inline-asm loads
// (global_load_dword) without compiler knowledge caused the R8 crash — the
// result VGPR gets reused before the load lands, then clobbered.
// Stage 2: gap > BAND certain; else exact f64 on {i1,i2} (fixupA); if even
// v1-v3 <= BAND (rare), full exact scan (fixupB).

typedef _Float16 f16;
typedef __attribute__((ext_vector_type(4))) _Float16 f16x4;
typedef __attribute__((ext_vector_type(8))) _Float16 f16x8;
typedef __attribute__((ext_vector_type(4))) float f32x4;

#define DDIM 512
#define KCODES 4096
#define BM 128
#define BN 256
#define NSTEP 256   // 16 chunks x 16 k-steps
#define BAND 0.25f
#define CAPB 4096

__device__ __forceinline__ void gload_lds16(const void* g, void* l) {
  __builtin_amdgcn_global_load_lds(
      (const __attribute__((address_space(1))) void*)g,
      (__attribute__((address_space(3))) void*)l, 16, 0, 0);
}

// -------- conversion: f32 -> hi f16 ------------------------------------------
__global__ void convert_hi(const float* __restrict__ in, f16* __restrict__ hi, int n4) {
  int stride = gridDim.x * blockDim.x;
  for (int i = blockIdx.x * blockDim.x + threadIdx.x; i < n4; i += stride) {
    float4 v = ((const float4*)in)[i];
    f16x4 h;
    h[0] = (_Float16)v.x; h[1] = (_Float16)v.y;
    h[2] = (_Float16)v.z; h[3] = (_Float16)v.w;
    ((f16x4*)hi)[i] = h;
  }
}

// -------- esqh = 0.5*||e||^2, one wave per code row, f64 accumulation --------
__global__ void esq_kernel(const float* __restrict__ e, float* __restrict__ esqh) {
  int gw = (blockIdx.x * blockDim.x + threadIdx.x) >> 6;
  int lane = threadIdx.x & 63;
  if (gw >= KCODES) return;
  const float4* row = (const float4*)(e + (size_t)gw * DDIM);
  float4 a = row[lane * 2];
  float4 b = row[lane * 2 + 1];
  double s = (double)a.x * a.x + (double)a.y * a.y + (double)a.z * a.z + (double)a.w * a.w +
             (double)b.x * b.x + (double)b.y * b.y + (double)b.z * b.z + (double)b.w * b.w;
#pragma unroll
  for (int m = 32; m; m >>= 1) s += __shfl_xor(s, m, 64);
  if (lane == 0) esqh[gw] = (float)(0.5 * s);
}

__global__ void zero2(int* c) { c[0] = 0; c[1] = 0; }

// -------- stage 1 ------------------------------------------------------------
// grid = 256 blocks (1/CU), 512 thr (8 waves: 2 row x 4 code).
// LDS: A[128][1024B] @0 (swz byte^=(row&7)<<4), B dbuf @131072 2x16KB
// ([256][64B], swz byte^=((row&3)^((row>>2)&3))<<4).
__global__ __launch_bounds__(512, 2) void vq_main(
    const f16* __restrict__ Ah, const f16* __restrict__ Bh,
    const float* __restrict__ esqh, float* __restrict__ outIdx,
    int4* __restrict__ listA, int* __restrict__ listB, int* __restrict__ cnts) {
  __shared__ char lds[163840];
  char* const ldsB = lds + 131072;
  const int tid = threadIdx.x;
  const int lane = tid & 63;
  const int wv = tid >> 6;     // 0..7
  const int wr = wv >> 2;      // row half
  const int wc = wv & 3;       // code quarter
  const int l15 = lane & 15, lg = lane >> 4;
  const int rowbase = blockIdx.x * BM;

  // ---- prologue: A resident (staged once, source pre-XORed, linear dest) ----
  const int aStageOff = ((lane * 16) ^ (wv << 4)) >> 1;  // f16 units; row&7==wv
  {
    const f16* aSrc = Ah + (size_t)(rowbase + wv) * DDIM + aStageOff;
    char* aDst = lds + wv * 1024;
#pragma unroll
    for (int t = 0; t < 16; ++t)
      gload_lds16(aSrc + (size_t)t * 8 * DDIM, aDst + t * 8192);
  }
  // B staging bases (swizzle baked into source column)
  const int bSwz = ((((tid >> 2) & 3) ^ ((tid >> 4) & 3)) << 4);
  const int bCol = (((tid & 3) * 16) ^ bSwz) >> 1;  // f16 units
  const f16* bSrc0 = Bh + (size_t)(tid >> 2) * DDIM + bCol;
  const f16* bSrc1 = Bh + (size_t)((tid >> 2) + 128) * DDIM + bCol;
  char* const bDstT = ldsB + wv * 1024;  // + buf*16384 + r*8192 (+lane*16 HW)
  gload_lds16(bSrc0, bDstT);             // chunk0 kstep0 -> buf0
  gload_lds16(bSrc1, bDstT + 8192);
  __syncthreads();  // full drain once

  // read bases
  const int swzA = (l15 & 7) << 4;
  const int swzBr = ((l15 & 3) ^ ((l15 >> 2) & 3)) << 4;
  const char* const aReadBase = lds + (wr * 64 + l15) * 1024;  // + i*16384 + acol
  const char* const bReadBase = ldsB + (wc * 64 + l15) * 64 + ((lg * 16) ^ swzBr);

  f32x4 acc[4][4];
  float esqv[4];
  float v1[16], v2[16], v3[16];
  int i1[16], i2[16];
#pragma unroll
  for (int t = 0; t < 16; ++t) { v1[t] = v2[t] = v3[t] = -3.4e38f; i1[t] = i2[t] = 0; }

#pragma unroll 1
  for (int s = 0; s < NSTEP; ++s) {
    const int ch = s >> 4, ks = s & 15, cur = s & 1;
    if (ks == 0) {
      // NORMAL loads (compiler-tracked: it inserts the right waitcnt before
      // first use at ks==15; our manual vmcnt(6) below still retires exactly
      // the previous step's 2 stage loads).
#pragma unroll
      for (int j = 0; j < 4; ++j)
        esqv[j] = esqh[ch * 256 + wc * 64 + j * 16 + l15];
#pragma unroll
      for (int i = 0; i < 4; ++i)
#pragma unroll
        for (int j = 0; j < 4; ++j) acc[i][j] = (f32x4){0.f, 0.f, 0.f, 0.f};
    }
    if (s + 1 < NSTEP) {
      const int ns = s + 1;
      const int off = (ns >> 4) * (BN * DDIM) + (ns & 15) * 32;  // f16 units
      char* bd = ldsB + ((ns & 1) ? 16384 : 0) + wv * 1024;
      gload_lds16(bSrc0 + off, bd);
      gload_lds16(bSrc1 + off, bd + 8192);
      if (ks == 0) asm volatile("s_waitcnt vmcnt(6)" ::: "memory");  // prev2 done; esq4+next2 fly
      else         asm volatile("s_waitcnt vmcnt(2)" ::: "memory");  // prev2 done; next2 fly
    } else {
      asm volatile("s_waitcnt vmcnt(0)" ::: "memory");
    }
    __builtin_amdgcn_s_barrier();

    const int acol = (ks * 64 + lg * 16) ^ swzA;
    f16x8 af[4], bf[4];
#pragma unroll
    for (int i = 0; i < 4; ++i) af[i] = *(const f16x8*)(aReadBase + i * 16384 + acol);
    const char* bb = bReadBase + cur * 16384;
#pragma unroll
    for (int j = 0; j < 4; ++j) bf[j] = *(const f16x8*)(bb + j * 1024);
#pragma unroll
    for (int i = 0; i < 4; ++i)
#pragma unroll
      for (int j = 0; j < 4; ++j)
        acc[i][j] = __builtin_amdgcn_mfma_f32_16x16x32_f16(af[i], bf[j], acc[i][j], 0, 0, 0);

    if (ks == 15) {  // chunk epilogue: registers only
#pragma unroll
      for (int j = 0; j < 4; ++j) {
        const int code = ch * 256 + wc * 64 + j * 16 + l15;
        const float eh = esqv[j];
#pragma unroll
        for (int i = 0; i < 4; ++i)
#pragma unroll
          for (int r = 0; r < 4; ++r) {
            float v = acc[i][j][r] - eh;
            int t = i * 4 + r;
            if (v > v1[t]) { v3[t] = v2[t]; v2[t] = v1[t]; i2[t] = i1[t]; v1[t] = v; i1[t] = code; }
            else if (v > v2[t]) { v3[t] = v2[t]; v2[t] = v; i2[t] = code; }
            else if (v > v3[t]) v3[t] = v;
          }
      }
    }
    __builtin_amdgcn_s_barrier();
  }

  // ---- butterfly top-3 merge over the 16 l15 lanes --------------------------
#pragma unroll
  for (int m = 1; m < 16; m <<= 1) {
#pragma unroll
    for (int t = 0; t < 16; ++t) {
      float ov1 = __shfl_xor(v1[t], m, 64);
      int oi1 = __shfl_xor(i1[t], m, 64);
      float ov2 = __shfl_xor(v2[t], m, 64);
      int oi2 = __shfl_xor(i2[t], m, 64);
      float ov3 = __shfl_xor(v3[t], m, 64);
      if (ov1 > v1[t] || (ov1 == v1[t] && oi1 < i1[t])) {
        if (v1[t] > ov2 || (v1[t] == ov2 && i1[t] < oi2)) {
          v3[t] = fmaxf(ov2, v2[t]); v2[t] = v1[t]; i2[t] = i1[t];
        } else {
          v3[t] = fmaxf(v1[t], ov3); v2[t] = ov2; i2[t] = oi2;
        }
        v1[t] = ov1; i1[t] = oi1;
      } else {
        if (ov1 > v2[t] || (ov1 == v2[t] && oi1 < i2[t])) {
          v3[t] = fmaxf(v2[t], ov2); v2[t] = ov1; i2[t] = oi1;
        } else {
          v3[t] = fmaxf(ov1, v3[t]);
        }
      }
    }
  }
  __syncthreads();
  // ---- cross-wave merge via LDS scratch (reuses B region) -------------------
  if (l15 == 0) {
    float* scr = (float*)ldsB;
#pragma unroll
    for (int t = 0; t < 16; ++t) {
      int rloc = wr * 64 + (t >> 2) * 16 + lg * 4 + (t & 3);
      float* e = scr + (rloc * 4 + wc) * 8;
      e[0] = v1[t]; e[1] = __int_as_float(i1[t]);
      e[2] = v2[t]; e[3] = __int_as_float(i2[t]);
      e[4] = v3[t];
    }
  }
  __syncthreads();
  if (tid < BM) {
    const float* scr = (const float*)ldsB;
    float m1 = 0.f, m2 = 0.f, m3 = 0.f;
    int j1 = 0, j2 = 0;
#pragma unroll
    for (int q = 0; q < 4; ++q) {
      const float* e = scr + (tid * 4 + q) * 8;
      float b1 = e[0]; int bi1 = __float_as_int(e[1]);
      float b2 = e[2]; int bi2 = __float_as_int(e[3]);
      float b3 = e[4];
      if (q == 0) { m1 = b1; j1 = bi1; m2 = b2; j2 = bi2; m3 = b3; continue; }
      if (b1 > m1 || (b1 == m1 && bi1 < j1)) {
        if (m1 > b2 || (m1 == b2 && j1 < bi2)) { m3 = fmaxf(b2, m2); m2 = m1; j2 = j1; }
        else { m3 = fmaxf(m1, b3); m2 = b2; j2 = bi2; }
        m1 = b1; j1 = bi1;
      } else {
        if (b1 > m2 || (b1 == m2 && bi1 < j2)) { m3 = fmaxf(m2, b2); m2 = b1; j2 = bi1; }
        else { m3 = fmaxf(b1, m3); }
      }
    }
    int row = rowbase + tid;
    outIdx[row] = (float)j1;
    if (m1 - m2 <= BAND) { int p = atomicAdd(&cnts[0], 1); listA[p] = make_int4(row, j1, j2, 0); }
    if (m1 - m3 <= BAND) { int p = atomicAdd(&cnts[1], 1); listB[p] = row; }
  }
}

#define DOT8(s, xa, xb, ea, eb)                                    \
  s += ((double)xa.x - 0.5 * (double)ea.x) * (double)ea.x;         \
  s += ((double)xa.y - 0.5 * (double)ea.y) * (double)ea.y;         \
  s += ((double)xa.z - 0.5 * (double)ea.z) * (double)ea.z;         \
  s += ((double)xa.w - 0.5 * (double)ea.w) * (double)ea.w;         \
  s += ((double)xb.x - 0.5 * (double)eb.x) * (double)eb.x;         \
  s += ((double)xb.y - 0.5 * (double)eb.y) * (double)eb.y;         \
  s += ((double)xb.z - 0.5 * (double)eb.z) * (double)eb.z;         \
  s += ((double)xb.w - 0.5 * (double)eb.w) * (double)eb.w;

// -------- fixupA: exact f64 re-score of {i1,i2}, one wave per entry ----------
__global__ void fixupA(const float* __restrict__ x, const float* __restrict__ embed,
                       const int* __restrict__ cnts, const int4* __restrict__ listA,
                       float* __restrict__ outIdx) {
  int gw = (blockIdx.x * blockDim.x + threadIdx.x) >> 6;
  int lane = threadIdx.x & 63;
  int nw = (gridDim.x * blockDim.x) >> 6;
  int n = cnts[0];
  for (int u = gw; u < n; u += nw) {
    int4 e = listA[u];
    const float4* xp = (const float4*)(x + (size_t)e.x * DDIM);
    float4 xa = xp[lane * 2], xb = xp[lane * 2 + 1];
    double d0, d1;
    {
      const float4* ep = (const float4*)(embed + (size_t)e.y * DDIM);
      float4 ea = ep[lane * 2], eb = ep[lane * 2 + 1];
      double s = 0.0; DOT8(s, xa, xb, ea, eb);
#pragma unroll
      for (int m = 32; m; m >>= 1) s += __shfl_xor(s, m, 64);
      d0 = s;
    }
    {
      const float4* ep = (const float4*)(embed + (size_t)e.z * DDIM);
      float4 ea = ep[lane * 2], eb = ep[lane * 2 + 1];
      double s = 0.0; DOT8(s, xa, xb, ea, eb);
#pragma unroll
      for (int m = 32; m; m >>= 1) s += __shfl_xor(s, m, 64);
      d1 = s;
    }
    if (lane == 0) {
      int best = (d1 > d0 || (d1 == d0 && e.z < e.y)) ? e.z : e.y;
      outIdx[e.x] = (float)best;
    }
  }
}

// -------- fixupB: full exact scan for rare rows; 8 blocks/row + merge --------
__global__ __launch_bounds__(256) void fixupB(
    const float* __restrict__ x, const float* __restrict__ embed,
    const int* __restrict__ cnts, const int* __restrict__ listB,
    double2* __restrict__ fbParts) {
  __shared__ double sv[4];
  __shared__ int si[4];
  int tid = threadIdx.x, lane = tid & 63, wv = tid >> 6;
  int nB = cnts[1]; if (nB > CAPB) nB = CAPB;
  for (int u = blockIdx.x; u < nB * 8; u += gridDim.x) {
    int entry = u >> 3, oct = u & 7;
    int row = listB[entry];
    const float4* xp = (const float4*)(x + (size_t)row * DDIM);
    float4 xa = xp[lane * 2], xb = xp[lane * 2 + 1];
    double bv = -1e300; int bi = 0;
    int cbase = oct * 512 + wv * 128;
#pragma unroll 1
    for (int k = 0; k < 128; ++k) {
      int c = cbase + k;
      const float4* ep = (const float4*)(embed + (size_t)c * DDIM);
      float4 ea = ep[lane * 2], eb = ep[lane * 2 + 1];
      double s = 0.0; DOT8(s, xa, xb, ea, eb);
#pragma unroll
      for (int m = 32; m; m >>= 1) s += __shfl_xor(s, m, 64);
      if (s > bv) { bv = s; bi = c; }
    }
    if (lane == 0) { sv[wv] = bv; si[wv] = bi; }
    __syncthreads();
    if (tid == 0) {
      double b = sv[0]; int bidx = si[0];
#pragma unroll
      for (int w = 1; w < 4; ++w)
        if (sv[w] > b || (sv[w] == b && si[w] < bidx)) { b = sv[w]; bidx = si[w]; }
      fbParts[entry * 8 + oct] = make_double2(b, (double)bidx);
    }
    __syncthreads();
  }
}

__global__ void fixupB2(const int* __restrict__ cnts, const int* __restrict__ listB,
                        const double2* __restrict__ fbParts, float* __restrict__ outIdx) {
  int nB = cnts[1]; if (nB > CAPB) nB = CAPB;
  for (int e = threadIdx.x; e < nB; e += blockDim.x) {
    double bv = -1e300; int bi = 0;
#pragma unroll
    for (int q = 0; q < 8; ++q) {
      double2 p = fbParts[e * 8 + q];
      int pi = (int)p.y;
      if (p.x > bv || (p.x == bv && pi < bi)) { bv = p.x; bi = pi; }
    }
    outIdx[listB[e]] = (float)bi;
  }
}

// -------- decode gather ------------------------------------------------------
__global__ void decode(const float* __restrict__ embed, const float* __restrict__ outIdx,
                       float* __restrict__ outQ, int nRows) {
  int gw = (blockIdx.x * blockDim.x + threadIdx.x) >> 6;
  int lane = threadIdx.x & 63;
  if (gw >= nRows) return;
  int bi = (int)outIdx[gw];
  const float4* src = (const float4*)(embed + (size_t)bi * DDIM);
  float4* dst = (float4*)(outQ + (size_t)gw * DDIM);
  dst[lane] = src[lane];
  dst[lane + 64] = src[lane + 64];
}

extern "C" void kernel_launch(void* const* d_in, const int* in_sizes, int n_in,
                              void* d_out, int out_size, void* d_ws, size_t ws_size,
                              hipStream_t stream) {
  const float* x = (const float*)d_in[0];
  const float* embed = (const float*)d_in[1];
  int nX = in_sizes[0];        // 16*2048*512
  int nRows = nX / DDIM;       // 32768
  int nRowBlocks = nRows / BM; // 256

  float* out = (float*)d_out;
  float* outIdx = out;
  float* outQ = out + nRows;

  size_t szA = (size_t)nRows * DDIM * sizeof(f16);    // 32 MiB
  size_t szB = (size_t)KCODES * DDIM * sizeof(f16);   // 4 MiB
  size_t szEsq = (size_t)KCODES * sizeof(float);      // 16 KiB
  size_t szLA = (size_t)nRows * sizeof(int4);         // 512 KiB
  size_t szLB = (size_t)nRows * sizeof(int);          // 128 KiB
  size_t szFB = (size_t)CAPB * 8 * sizeof(double2);   // 512 KiB

  char* ws = (char*)d_ws;
  f16 *Ah, *Bh;
  float* esqh;
  int4* listA;
  int* listB;
  double2* fbParts;
  int* cnts;
  size_t needFull = szA + szB + szEsq + szLA + szLB + szFB + 64;
  if (ws_size >= needFull) {
    Ah = (f16*)ws;
    Bh = (f16*)(ws + szA);
    esqh = (float*)(ws + szA + szB);
    listA = (int4*)(ws + szA + szB + szEsq);
    listB = (int*)(ws + szA + szB + szEsq + szLA);
    fbParts = (double2*)(ws + szA + szB + szEsq + szLA + szLB);
    cnts = (int*)(ws + szA + szB + szEsq + szLA + szLB + szFB);
  } else {
    // quantize region of d_out (64 MiB) holds Ah; decode overwrites it at end
    Ah = (f16*)outQ;
    Bh = (f16*)ws;
    esqh = (float*)(ws + szB);
    listA = (int4*)(ws + szB + szEsq);
    listB = (int*)(ws + szB + szEsq + szLA);
    fbParts = (double2*)(ws + szB + szEsq + szLA + szLB);
    cnts = (int*)(ws + szB + szEsq + szLA + szLB + szFB);
  }

  int n4x = nX / 4;
  int n4e = in_sizes[1] / 4;
  hipLaunchKernelGGL(convert_hi, dim3(2048), dim3(256), 0, stream, x, Ah, n4x);
  hipLaunchKernelGGL(convert_hi, dim3((n4e + 255) / 256), dim3(256), 0, stream, embed, Bh, n4e);
  hipLaunchKernelGGL(esq_kernel, dim3(KCODES / 4), dim3(256), 0, stream, embed, esqh);
  hipLaunchKernelGGL(zero2, dim3(1), dim3(1), 0, stream, cnts);
  hipLaunchKernelGGL(vq_main, dim3(nRowBlocks), dim3(512), 0, stream,
                     Ah, Bh, esqh, outIdx, listA, listB, cnts);
  hipLaunchKernelGGL(fixupA, dim3(256), dim3(256), 0, stream, x, embed, cnts, listA, outIdx);
  hipLaunchKernelGGL(fixupB, dim3(1024), dim3(256), 0, stream, x, embed, cnts, listB, fbParts);
  hipLaunchKernelGGL(fixupB2, dim3(1), dim3(256), 0, stream, cnts, listB, fbParts, outIdx);
  hipLaunchKernelGGL(decode, dim3(nRows / 4), dim3(256), 0, stream,
                     embed, outIdx, outQ, nRows);
}

// Round 10
// 504.228 us; speedup vs baseline: 12.1003x; 12.1003x over previous
//
#include <hip/hip_runtime.h>
#include <hip/hip_fp16.h>
#include <stdint.h>

// Problem: x[16,2048,512] f32, embed[4096,512] f32.
// encode: idx[n] = argmax_k (x.e_k - 0.5||e_k||^2); decode: embed[idx].
// d_out (float): [0,32768) = idx, [32768,+32768*512) = quantize.
//
// Stage 1 (vq_main): hi-f16 MFMA GEMM, A-tile LDS-RESIDENT (staged once: 32 MB
// total HBM), B streamed from L2 in dbuf [256][32] tiles with counted vmcnt.
// 512 thr / 8 waves; wave tile 32 rows x 128 codes (4x2 wave grid) -> per-lane
// argmax state is 8 slots (40 regs), acc[2][8]=64. __launch_bounds__(512,1):
// hipcc's 2nd arg is min BLOCKS/CU (CUDA semantics) — R9's (512,2) capped
// VGPRs at 128 and spilled 19 GB of scratch (WRITE_SIZE 13.9 GB, 4.7 ms).
// Stage 2: gap > BAND certain; else exact f64 on {i1,i2} (fixupA); if even
// v1-v3 <= BAND (rare), full exact scan (fixupB).

typedef _Float16 f16;
typedef __attribute__((ext_vector_type(4))) _Float16 f16x4;
typedef __attribute__((ext_vector_type(8))) _Float16 f16x8;
typedef __attribute__((ext_vector_type(4))) float f32x4;

#define DDIM 512
#define KCODES 4096
#define BM 128
#define BN 256
#define NSTEP 256   // 16 chunks x 16 k-steps
#define BAND 0.25f
#define CAPB 4096

__device__ __forceinline__ void gload_lds16(const void* g, void* l) {
  __builtin_amdgcn_global_load_lds(
      (const __attribute__((address_space(1))) void*)g,
      (__attribute__((address_space(3))) void*)l, 16, 0, 0);
}

// -------- conversion: f32 -> hi f16 ------------------------------------------
__global__ void convert_hi(const float* __restrict__ in, f16* __restrict__ hi, int n4) {
  int stride = gridDim.x * blockDim.x;
  for (int i = blockIdx.x * blockDim.x + threadIdx.x; i < n4; i += stride) {
    float4 v = ((const float4*)in)[i];
    f16x4 h;
    h[0] = (_Float16)v.x; h[1] = (_Float16)v.y;
    h[2] = (_Float16)v.z; h[3] = (_Float16)v.w;
    ((f16x4*)hi)[i] = h;
  }
}

// -------- esqh = 0.5*||e||^2, one wave per code row, f64 accumulation --------
__global__ void esq_kernel(const float* __restrict__ e, float* __restrict__ esqh) {
  int gw = (blockIdx.x * blockDim.x + threadIdx.x) >> 6;
  int lane = threadIdx.x & 63;
  if (gw >= KCODES) return;
  const float4* row = (const float4*)(e + (size_t)gw * DDIM);
  float4 a = row[lane * 2];
  float4 b = row[lane * 2 + 1];
  double s = (double)a.x * a.x + (double)a.y * a.y + (double)a.z * a.z + (double)a.w * a.w +
             (double)b.x * b.x + (double)b.y * b.y + (double)b.z * b.z + (double)b.w * b.w;
#pragma unroll
  for (int m = 32; m; m >>= 1) s += __shfl_xor(s, m, 64);
  if (lane == 0) esqh[gw] = (float)(0.5 * s);
}

__global__ void zero2(int* c) { c[0] = 0; c[1] = 0; }

// -------- stage 1 ------------------------------------------------------------
// grid = 256 blocks (1/CU), 512 thr (8 waves: 4 row-quarters x 2 code-halves).
// LDS: A[128][1024B] @0 (swz byte^=(row&7)<<4), B dbuf @131072 2x16KB
// ([256][64B], swz byte^=((row&3)^((row>>2)&3))<<4).
__global__ __launch_bounds__(512, 1) void vq_main(
    const f16* __restrict__ Ah, const f16* __restrict__ Bh,
    const float* __restrict__ esqh, float* __restrict__ outIdx,
    int4* __restrict__ listA, int* __restrict__ listB, int* __restrict__ cnts) {
  __shared__ char lds[163840];
  char* const ldsB = lds + 131072;
  const int tid = threadIdx.x;
  const int lane = tid & 63;
  const int wv = tid >> 6;     // 0..7
  const int wr = wv >> 1;      // 0..3: 32-row quarter
  const int wc = wv & 1;       // 0..1: 128-code half
  const int l15 = lane & 15, lg = lane >> 4;
  const int rowbase = blockIdx.x * BM;

  // ---- prologue: A resident (staged once, source pre-XORed, linear dest) ----
  const int aStageOff = ((lane * 16) ^ (wv << 4)) >> 1;  // f16 units; row&7==wv
  {
    const f16* aSrc = Ah + (size_t)(rowbase + wv) * DDIM + aStageOff;
    char* aDst = lds + wv * 1024;
#pragma unroll
    for (int t = 0; t < 16; ++t)
      gload_lds16(aSrc + (size_t)t * 8 * DDIM, aDst + t * 8192);
  }
  // B staging bases (swizzle baked into source column)
  const int bSwz = ((((tid >> 2) & 3) ^ ((tid >> 4) & 3)) << 4);
  const int bCol = (((tid & 3) * 16) ^ bSwz) >> 1;  // f16 units
  const f16* bSrc0 = Bh + (size_t)(tid >> 2) * DDIM + bCol;
  const f16* bSrc1 = Bh + (size_t)((tid >> 2) + 128) * DDIM + bCol;
  char* const bDstT = ldsB + wv * 1024;  // + buf*16384 + r*8192 (+lane*16 HW)
  gload_lds16(bSrc0, bDstT);             // chunk0 kstep0 -> buf0
  gload_lds16(bSrc1, bDstT + 8192);
  __syncthreads();  // full drain once

  // read bases
  const int swzA = (l15 & 7) << 4;
  const int swzBr = ((l15 & 3) ^ ((l15 >> 2) & 3)) << 4;
  const char* const aReadBase = lds + (wr * 32 + l15) * 1024;  // + i*16384 + acol
  const char* const bReadBase = ldsB + (wc * 128 + l15) * 64 + ((lg * 16) ^ swzBr);

  f32x4 acc[2][8];
  float esqv[8];
  float v1[8], v2[8], v3[8];
  int i1[8], i2[8];
#pragma unroll
  for (int t = 0; t < 8; ++t) { v1[t] = v2[t] = v3[t] = -3.4e38f; i1[t] = i2[t] = 0; }

#pragma unroll 1
  for (int s = 0; s < NSTEP; ++s) {
    const int ch = s >> 4, ks = s & 15, cur = s & 1;
    if (ks == 0) {
      // compiler-tracked loads; retired by vmcnt(10) accounting below
#pragma unroll
      for (int j = 0; j < 8; ++j)
        esqv[j] = esqh[ch * 256 + wc * 128 + j * 16 + l15];
#pragma unroll
      for (int i = 0; i < 2; ++i)
#pragma unroll
        for (int j = 0; j < 8; ++j) acc[i][j] = (f32x4){0.f, 0.f, 0.f, 0.f};
    }
    if (s + 1 < NSTEP) {
      const int ns = s + 1;
      const int off = (ns >> 4) * (BN * DDIM) + (ns & 15) * 32;  // f16 units
      char* bd = ldsB + ((ns & 1) ? 16384 : 0) + wv * 1024;
      gload_lds16(bSrc0 + off, bd);
      gload_lds16(bSrc1 + off, bd + 8192);
      // in flight: [prev stage 2] + [esq 8 if ks==0] + [next stage 2]
      if (ks == 0) asm volatile("s_waitcnt vmcnt(10)" ::: "memory");
      else         asm volatile("s_waitcnt vmcnt(2)" ::: "memory");
    } else {
      asm volatile("s_waitcnt vmcnt(0)" ::: "memory");
    }
    __builtin_amdgcn_s_barrier();

    const int acol = (ks * 64 + lg * 16) ^ swzA;
    f16x8 af0 = *(const f16x8*)(aReadBase + acol);
    f16x8 af1 = *(const f16x8*)(aReadBase + 16384 + acol);
    const char* bb = bReadBase + cur * 16384;
#pragma unroll
    for (int j = 0; j < 8; ++j) {
      f16x8 bf = *(const f16x8*)(bb + j * 1024);
      acc[0][j] = __builtin_amdgcn_mfma_f32_16x16x32_f16(af0, bf, acc[0][j], 0, 0, 0);
      acc[1][j] = __builtin_amdgcn_mfma_f32_16x16x32_f16(af1, bf, acc[1][j], 0, 0, 0);
    }

    if (ks == 15) {  // chunk epilogue: registers only
#pragma unroll
      for (int j = 0; j < 8; ++j) {
        const int code = ch * 256 + wc * 128 + j * 16 + l15;
        const float eh = esqv[j];
#pragma unroll
        for (int i = 0; i < 2; ++i)
#pragma unroll
          for (int r = 0; r < 4; ++r) {
            float v = acc[i][j][r] - eh;
            int t = i * 4 + r;
            if (v > v1[t]) { v3[t] = v2[t]; v2[t] = v1[t]; i2[t] = i1[t]; v1[t] = v; i1[t] = code; }
            else if (v > v2[t]) { v3[t] = v2[t]; v2[t] = v; i2[t] = code; }
            else if (v > v3[t]) v3[t] = v;
          }
      }
    }
    __builtin_amdgcn_s_barrier();
  }

  // ---- butterfly top-3 merge over the 16 l15 lanes --------------------------
#pragma unroll
  for (int m = 1; m < 16; m <<= 1) {
#pragma unroll
    for (int t = 0; t < 8; ++t) {
      float ov1 = __shfl_xor(v1[t], m, 64);
      int oi1 = __shfl_xor(i1[t], m, 64);
      float ov2 = __shfl_xor(v2[t], m, 64);
      int oi2 = __shfl_xor(i2[t], m, 64);
      float ov3 = __shfl_xor(v3[t], m, 64);
      if (ov1 > v1[t] || (ov1 == v1[t] && oi1 < i1[t])) {
        if (v1[t] > ov2 || (v1[t] == ov2 && i1[t] < oi2)) {
          v3[t] = fmaxf(ov2, v2[t]); v2[t] = v1[t]; i2[t] = i1[t];
        } else {
          v3[t] = fmaxf(v1[t], ov3); v2[t] = ov2; i2[t] = oi2;
        }
        v1[t] = ov1; i1[t] = oi1;
      } else {
        if (ov1 > v2[t] || (ov1 == v2[t] && oi1 < i2[t])) {
          v3[t] = fmaxf(v2[t], ov2); v2[t] = ov1; i2[t] = oi1;
        } else {
          v3[t] = fmaxf(ov1, v3[t]);
        }
      }
    }
  }
  __syncthreads();
  // ---- cross-wave merge via LDS scratch (reuses B region; 2 entries/row) ----
  if (l15 == 0) {
    float* scr = (float*)ldsB;
#pragma unroll
    for (int t = 0; t < 8; ++t) {
      int rloc = wr * 32 + (t >> 2) * 16 + lg * 4 + (t & 3);
      float* e = scr + (rloc * 2 + wc) * 8;
      e[0] = v1[t]; e[1] = __int_as_float(i1[t]);
      e[2] = v2[t]; e[3] = __int_as_float(i2[t]);
      e[4] = v3[t];
    }
  }
  __syncthreads();
  if (tid < BM) {
    const float* scr = (const float*)ldsB;
    float m1 = 0.f, m2 = 0.f, m3 = 0.f;
    int j1 = 0, j2 = 0;
#pragma unroll
    for (int q = 0; q < 2; ++q) {
      const float* e = scr + (tid * 2 + q) * 8;
      float b1 = e[0]; int bi1 = __float_as_int(e[1]);
      float b2 = e[2]; int bi2 = __float_as_int(e[3]);
      float b3 = e[4];
      if (q == 0) { m1 = b1; j1 = bi1; m2 = b2; j2 = bi2; m3 = b3; continue; }
      if (b1 > m1 || (b1 == m1 && bi1 < j1)) {
        if (m1 > b2 || (m1 == b2 && j1 < bi2)) { m3 = fmaxf(b2, m2); m2 = m1; j2 = j1; }
        else { m3 = fmaxf(m1, b3); m2 = b2; j2 = bi2; }
        m1 = b1; j1 = bi1;
      } else {
        if (b1 > m2 || (b1 == m2 && bi1 < j2)) { m3 = fmaxf(m2, b2); m2 = b1; j2 = bi1; }
        else { m3 = fmaxf(b1, m3); }
      }
    }
    int row = rowbase + tid;
    outIdx[row] = (float)j1;
    if (m1 - m2 <= BAND) { int p = atomicAdd(&cnts[0], 1); listA[p] = make_int4(row, j1, j2, 0); }
    if (m1 - m3 <= BAND) { int p = atomicAdd(&cnts[1], 1); listB[p] = row; }
  }
}

#define DOT8(s, xa, xb, ea, eb)                                    \
  s += ((double)xa.x - 0.5 * (double)ea.x) * (double)ea.x;         \
  s += ((double)xa.y - 0.5 * (double)ea.y) * (double)ea.y;         \
  s += ((double)xa.z - 0.5 * (double)ea.z) * (double)ea.z;         \
  s += ((double)xa.w - 0.5 * (double)ea.w) * (double)ea.w;         \
  s += ((double)xb.x - 0.5 * (double)eb.x) * (double)eb.x;         \
  s += ((double)xb.y - 0.5 * (double)eb.y) * (double)eb.y;         \
  s += ((double)xb.z - 0.5 * (double)eb.z) * (double)eb.z;         \
  s += ((double)xb.w - 0.5 * (double)eb.w) * (double)eb.w;

// -------- fixupA: exact f64 re-score of {i1,i2}, one wave per entry ----------
__global__ void fixupA(const float* __restrict__ x, const float* __restrict__ embed,
                       const int* __restrict__ cnts, const int4* __restrict__ listA,
                       float* __restrict__ outIdx) {
  int gw = (blockIdx.x * blockDim.x + threadIdx.x) >> 6;
  int lane = threadIdx.x & 63;
  int nw = (gridDim.x * blockDim.x) >> 6;
  int n = cnts[0];
  for (int u = gw; u < n; u += nw) {
    int4 e = listA[u];
    const float4* xp = (const float4*)(x + (size_t)e.x * DDIM);
    float4 xa = xp[lane * 2], xb = xp[lane * 2 + 1];
    double d0, d1;
    {
      const float4* ep = (const float4*)(embed + (size_t)e.y * DDIM);
      float4 ea = ep[lane * 2], eb = ep[lane * 2 + 1];
      double s = 0.0; DOT8(s, xa, xb, ea, eb);
#pragma unroll
      for (int m = 32; m; m >>= 1) s += __shfl_xor(s, m, 64);
      d0 = s;
    }
    {
      const float4* ep = (const float4*)(embed + (size_t)e.z * DDIM);
      float4 ea = ep[lane * 2], eb = ep[lane * 2 + 1];
      double s = 0.0; DOT8(s, xa, xb, ea, eb);
#pragma unroll
      for (int m = 32; m; m >>= 1) s += __shfl_xor(s, m, 64);
      d1 = s;
    }
    if (lane == 0) {
      int best = (d1 > d0 || (d1 == d0 && e.z < e.y)) ? e.z : e.y;
      outIdx[e.x] = (float)best;
    }
  }
}

// -------- fixupB: full exact scan for rare rows; 8 blocks/row + merge --------
__global__ __launch_bounds__(256) void fixupB(
    const float* __restrict__ x, const float* __restrict__ embed,
    const int* __restrict__ cnts, const int* __restrict__ listB,
    double2* __restrict__ fbParts) {
  __shared__ double sv[4];
  __shared__ int si[4];
  int tid = threadIdx.x, lane = tid & 63, wv = tid >> 6;
  int nB = cnts[1]; if (nB > CAPB) nB = CAPB;
  for (int u = blockIdx.x; u < nB * 8; u += gridDim.x) {
    int entry = u >> 3, oct = u & 7;
    int row = listB[entry];
    const float4* xp = (const float4*)(x + (size_t)row * DDIM);
    float4 xa = xp[lane * 2], xb = xp[lane * 2 + 1];
    double bv = -1e300; int bi = 0;
    int cbase = oct * 512 + wv * 128;
#pragma unroll 1
    for (int k = 0; k < 128; ++k) {
      int c = cbase + k;
      const float4* ep = (const float4*)(embed + (size_t)c * DDIM);
      float4 ea = ep[lane * 2], eb = ep[lane * 2 + 1];
      double s = 0.0; DOT8(s, xa, xb, ea, eb);
#pragma unroll
      for (int m = 32; m; m >>= 1) s += __shfl_xor(s, m, 64);
      if (s > bv) { bv = s; bi = c; }
    }
    if (lane == 0) { sv[wv] = bv; si[wv] = bi; }
    __syncthreads();
    if (tid == 0) {
      double b = sv[0]; int bidx = si[0];
#pragma unroll
      for (int w = 1; w < 4; ++w)
        if (sv[w] > b || (sv[w] == b && si[w] < bidx)) { b = sv[w]; bidx = si[w]; }
      fbParts[entry * 8 + oct] = make_double2(b, (double)bidx);
    }
    __syncthreads();
  }
}

__global__ void fixupB2(const int* __restrict__ cnts, const int* __restrict__ listB,
                        const double2* __restrict__ fbParts, float* __restrict__ outIdx) {
  int nB = cnts[1]; if (nB > CAPB) nB = CAPB;
  for (int e = threadIdx.x; e < nB; e += blockDim.x) {
    double bv = -1e300; int bi = 0;
#pragma unroll
    for (int q = 0; q < 8; ++q) {
      double2 p = fbParts[e * 8 + q];
      int pi = (int)p.y;
      if (p.x > bv || (p.x == bv && pi < bi)) { bv = p.x; bi = pi; }
    }
    outIdx[listB[e]] = (float)bi;
  }
}

// -------- decode gather ------------------------------------------------------
__global__ void decode(const float* __restrict__ embed, const float* __restrict__ outIdx,
                       float* __restrict__ outQ, int nRows) {
  int gw = (blockIdx.x * blockDim.x + threadIdx.x) >> 6;
  int lane = threadIdx.x & 63;
  if (gw >= nRows) return;
  int bi = (int)outIdx[gw];
  const float4* src = (const float4*)(embed + (size_t)bi * DDIM);
  float4* dst = (float4*)(outQ + (size_t)gw * DDIM);
  dst[lane] = src[lane];
  dst[lane + 64] = src[lane + 64];
}

extern "C" void kernel_launch(void* const* d_in, const int* in_sizes, int n_in,
                              void* d_out, int out_size, void* d_ws, size_t ws_size,
                              hipStream_t stream) {
  const float* x = (const float*)d_in[0];
  const float* embed = (const float*)d_in[1];
  int nX = in_sizes[0];        // 16*2048*512
  int nRows = nX / DDIM;       // 32768
  int nRowBlocks = nRows / BM; // 256

  float* out = (float*)d_out;
  float* outIdx = out;
  float* outQ = out + nRows;

  size_t szA = (size_t)nRows * DDIM * sizeof(f16);    // 32 MiB
  size_t szB = (size_t)KCODES * DDIM * sizeof(f16);   // 4 MiB
  size_t szEsq = (size_t)KCODES * sizeof(float);      // 16 KiB
  size_t szLA = (size_t)nRows * sizeof(int4);         // 512 KiB
  size_t szLB = (size_t)nRows * sizeof(int);          // 128 KiB
  size_t szFB = (size_t)CAPB * 8 * sizeof(double2);   // 512 KiB

  char* ws = (char*)d_ws;
  f16 *Ah, *Bh;
  float* esqh;
  int4* listA;
  int* listB;
  double2* fbParts;
  int* cnts;
  size_t needFull = szA + szB + szEsq + szLA + szLB + szFB + 64;
  if (ws_size >= needFull) {
    Ah = (f16*)ws;
    Bh = (f16*)(ws + szA);
    esqh = (float*)(ws + szA + szB);
    listA = (int4*)(ws + szA + szB + szEsq);
    listB = (int*)(ws + szA + szB + szEsq + szLA);
    fbParts = (double2*)(ws + szA + szB + szEsq + szLA + szLB);
    cnts = (int*)(ws + szA + szB + szEsq + szLA + szLB + szFB);
  } else {
    // quantize region of d_out (64 MiB) holds Ah; decode overwrites it at end
    Ah = (f16*)outQ;
    Bh = (f16*)ws;
    esqh = (float*)(ws + szB);
    listA = (int4*)(ws + szB + szEsq);
    listB = (int*)(ws + szB + szEsq + szLA);
    fbParts = (double2*)(ws + szB + szEsq + szLA + szLB);
    cnts = (int*)(ws + szB + szEsq + szLA + szLB + szFB);
  }

  int n4x = nX / 4;
  int n4e = in_sizes[1] / 4;
  hipLaunchKernelGGL(convert_hi, dim3(2048), dim3(256), 0, stream, x, Ah, n4x);
  hipLaunchKernelGGL(convert_hi, dim3((n4e + 255) / 256), dim3(256), 0, stream, embed, Bh, n4e);
  hipLaunchKernelGGL(esq_kernel, dim3(KCODES / 4), dim3(256), 0, stream, embed, esqh);
  hipLaunchKernelGGL(zero2, dim3(1), dim3(1), 0, stream, cnts);
  hipLaunchKernelGGL(vq_main, dim3(nRowBlocks), dim3(512), 0, stream,
                     Ah, Bh, esqh, outIdx, listA, listB, cnts);
  hipLaunchKernelGGL(fixupA, dim3(256), dim3(256), 0, stream, x, embed, cnts, listA, outIdx);
  hipLaunchKernelGGL(fixupB, dim3(1024), dim3(256), 0, stream, x, embed, cnts, listB, fbParts);
  hipLaunchKernelGGL(fixupB2, dim3(1), dim3(256), 0, stream, cnts, listB, fbParts, outIdx);
  hipLaunchKernelGGL(decode, dim3(nRows / 4), dim3(256), 0, stream,
                     embed, outIdx, outQ, nRows);
}